// Round 2
// 279.763 us; speedup vs baseline: 1.0216x; 1.0216x over previous
//
#include <hip/hip_runtime.h>
#include <cstdint>
#include <cstddef>

#define BN_EPS 1e-5f

typedef short bf16x8 __attribute__((ext_vector_type(8)));
typedef float f32x4  __attribute__((ext_vector_type(4)));
typedef unsigned short u16x8 __attribute__((ext_vector_type(8)));

__device__ __forceinline__ uint16_t f2bf_rte(float f) {
  uint32_t u = __float_as_uint(f);
  uint32_t r = u + 0x7fffu + ((u >> 16) & 1u);
  return (uint16_t)(r >> 16);
}
__device__ __forceinline__ float bf2f(uint16_t h) {
  return __uint_as_float(((uint32_t)h) << 16);
}
__device__ __forceinline__ void split_bf(float v, uint16_t& hi, uint16_t& lo) {
  hi = f2bf_rte(v);
  lo = f2bf_rte(v - bf2f(hi));
}

// async global->LDS (16B/lane). LDS dest is wave-uniform base + lane*16 (HW).
__device__ __forceinline__ void glds16(const uint16_t* g, uint16_t* l) {
  __builtin_amdgcn_global_load_lds(
      (const __attribute__((address_space(1))) uint32_t*)(const void*)g,
      (__attribute__((address_space(3))) uint32_t*)(void*)l, 16, 0, 0);
}

// ---------------- CSR build over dst ----------------
__global__ void zero_i32_k(int* p, int n) {
  int i = blockIdx.x * blockDim.x + threadIdx.x;
  if (i < n) p[i] = 0;
}

__global__ void hist_k(const int* __restrict__ dst, int* __restrict__ cnt, int E) {
  int e = blockIdx.x * blockDim.x + threadIdx.x;
  if (e < E) atomicAdd(&cnt[dst[e]], 1);
}

__global__ __launch_bounds__(1024) void scan_k(const int* __restrict__ cnt,
                                               int* __restrict__ offsets,
                                               int* __restrict__ cursor,
                                               int N, int total) {
  __shared__ int part[1024];
  int t = threadIdx.x;
  int a0 = cnt[4*t+0], a1 = cnt[4*t+1], a2 = cnt[4*t+2], a3 = cnt[4*t+3];
  part[t] = a0 + a1 + a2 + a3;
  __syncthreads();
  for (int off = 1; off < 1024; off <<= 1) {
    int v = (t >= off) ? part[t - off] : 0;
    __syncthreads();
    part[t] += v;
    __syncthreads();
  }
  int excl = (t == 0) ? 0 : part[t-1];
  int o0 = excl, o1 = o0 + a0, o2 = o1 + a1, o3 = o2 + a2;
  offsets[4*t+0] = o0; offsets[4*t+1] = o1; offsets[4*t+2] = o2; offsets[4*t+3] = o3;
  cursor [4*t+0] = o0; cursor [4*t+1] = o1; cursor [4*t+2] = o2; cursor [4*t+3] = o3;
  if (t == 0) offsets[N] = total;
}

__global__ void scatter_k(const int* __restrict__ dst, int* __restrict__ cursor,
                          int* __restrict__ csr, int E) {
  int e = blockIdx.x * blockDim.x + threadIdx.x;
  if (e < E) {
    int d = dst[e];
    int pos = atomicAdd(&cursor[d], 1);
    csr[pos] = e;
  }
}

// ---------------- W2'^T build: [cout][Kpad] bf16 hi/lo; k 0..31 W2, 32 b2, 33 root ----------------
__global__ void build_W2pT_k(const float* __restrict__ W2, const float* __restrict__ b2,
                             const float* __restrict__ root,
                             uint16_t* __restrict__ Bhi, uint16_t* __restrict__ Blo,
                             int cin, int cout, int Kpad) {
  int idx = blockIdx.x * blockDim.x + threadIdx.x;
  int total = cout * Kpad;
  if (idx >= total) return;
  int o  = idx / Kpad;
  int ki = idx - o * Kpad;
  float v = 0.f;
  if (ki < 34 * cin) {
    int k = ki / cin;
    int i = ki - k * cin;
    if (k < 32)       v = W2[(size_t)k * cin * cout + (size_t)i * cout + o];
    else if (k == 32) v = b2[(size_t)i * cout + o];
    else              v = root[(size_t)i * cout + o];
  }
  uint16_t hi, lo;
  split_bf(v, hi, lo);
  Bhi[idx] = hi;
  Blo[idx] = lo;
}

// ---------------- S build, vectorized (CIN in {64,128}), fused edge-MLP z ----------------
template<int CIN>
__global__ __launch_bounds__(256) void build_S_vec_k(const float* __restrict__ h,
                                                     const float* __restrict__ ea,
                                                     const float* __restrict__ W1,
                                                     const float* __restrict__ b1,
                                                     const int* __restrict__ src,
                                                     const int* __restrict__ csr,
                                                     const int* __restrict__ offsets,
                                                     uint16_t* __restrict__ Shi,
                                                     uint16_t* __restrict__ Slo,
                                                     int Kpad) {
  constexpr int CH = 8;
  constexpr int K1 = 33 * CIN;
  constexpr int NCH = K1 / 8;
  constexpr int NP = (NCH + 255) / 256;
  __shared__ float hs[CH][CIN];
  __shared__ float zs[CH][33];
  __shared__ int   es[CH];
  const int n = blockIdx.x;
  const int tid = threadIdx.x;
  const int base = offsets[n];
  const int deg  = offsets[n+1] - base;
  const float scale = 1.f / fmaxf((float)deg, 1.f);
  float acc[NP][8];
#pragma unroll
  for (int p = 0; p < NP; p++)
#pragma unroll
    for (int j = 0; j < 8; j++) acc[p][j] = 0.f;

  for (int c0 = 0; c0 < deg; c0 += CH) {
    const int cc = min(CH, deg - c0);
    if (tid < cc) es[tid] = csr[base + c0 + tid];
    __syncthreads();
    for (int idx = tid; idx < cc * CIN; idx += 256) {
      int slot = idx / CIN, i = idx - slot * CIN;
      hs[slot][i] = h[(size_t)src[es[slot]] * CIN + i];
    }
    for (int idx = tid; idx < cc * 33; idx += 256) {
      int slot = idx / 33, k = idx - slot * 33;
      float v;
      if (k == 32) v = 1.f;
      else {
        int e = es[slot];
        v = fmaxf(ea[e*3+0] * W1[k] + ea[e*3+1] * W1[32 + k] + ea[e*3+2] * W1[64 + k] + b1[k], 0.f);
      }
      zs[slot][k] = v;
    }
    __syncthreads();
#pragma unroll
    for (int p = 0; p < NP; p++) {
      int ch = p * 256 + tid;
      if (ch < NCH) {
        int ki0 = ch * 8;
        int k  = ki0 / CIN;
        int i0 = ki0 & (CIN - 1);
        for (int c = 0; c < cc; c++) {
          float zv = zs[c][k];
          float4 h0 = *(const float4*)&hs[c][i0];
          float4 h1 = *(const float4*)&hs[c][i0 + 4];
          acc[p][0] += zv * h0.x; acc[p][1] += zv * h0.y;
          acc[p][2] += zv * h0.z; acc[p][3] += zv * h0.w;
          acc[p][4] += zv * h1.x; acc[p][5] += zv * h1.y;
          acc[p][6] += zv * h1.z; acc[p][7] += zv * h1.w;
        }
      }
    }
    __syncthreads();
  }
  const size_t rowb = (size_t)n * Kpad;
#pragma unroll
  for (int p = 0; p < NP; p++) {
    int ch = p * 256 + tid;
    if (ch < NCH) {
      u16x8 hv, lv;
#pragma unroll
      for (int j = 0; j < 8; j++) {
        uint16_t hi, lo;
        split_bf(acc[p][j] * scale, hi, lo);
        hv[j] = hi; lv[j] = lo;
      }
      *(u16x8*)(Shi + rowb + ch * 8) = hv;
      *(u16x8*)(Slo + rowb + ch * 8) = lv;
    }
  }
  for (int c = tid; c < CIN / 8; c += 256) {
    int i0 = c * 8;
    float4 a = *(const float4*)&h[(size_t)n * CIN + i0];
    float4 b = *(const float4*)&h[(size_t)n * CIN + i0 + 4];
    float vals[8] = {a.x, a.y, a.z, a.w, b.x, b.y, b.z, b.w};
    u16x8 hv, lv;
#pragma unroll
    for (int j = 0; j < 8; j++) {
      uint16_t hi, lo;
      split_bf(vals[j], hi, lo);
      hv[j] = hi; lv[j] = lo;
    }
    *(u16x8*)(Shi + rowb + K1 + i0) = hv;
    *(u16x8*)(Slo + rowb + K1 + i0) = lv;
  }
  for (int ki = 34 * CIN + tid; ki < Kpad; ki += 256) {
    Shi[rowb + ki] = 0;
    Slo[rowb + ki] = 0;
  }
}

// scalar variant for CIN=5 (layer 1; tiny)
__global__ __launch_bounds__(256) void build_S5_k(const float* __restrict__ h,
                                                  const float* __restrict__ ea,
                                                  const float* __restrict__ W1,
                                                  const float* __restrict__ b1,
                                                  const int* __restrict__ src,
                                                  const int* __restrict__ csr,
                                                  const int* __restrict__ offsets,
                                                  uint16_t* __restrict__ Shi,
                                                  uint16_t* __restrict__ Slo,
                                                  int Kpad) {
  constexpr int CIN = 5, CH = 8;
  constexpr int K1 = 33 * CIN;   // 165
  constexpr int KT = 34 * CIN;   // 170
  __shared__ float hs[CH][CIN];
  __shared__ float zs[CH][33];
  __shared__ int   es[CH];
  const int n = blockIdx.x;
  const int tid = threadIdx.x;
  const int base = offsets[n];
  const int deg  = offsets[n+1] - base;
  const float scale = 1.f / fmaxf((float)deg, 1.f);
  float acc = 0.f;

  for (int c0 = 0; c0 < deg; c0 += CH) {
    const int cc = min(CH, deg - c0);
    if (tid < cc) es[tid] = csr[base + c0 + tid];
    __syncthreads();
    for (int idx = tid; idx < cc * CIN; idx += 256) {
      int slot = idx / CIN, i = idx - slot * CIN;
      hs[slot][i] = h[(size_t)src[es[slot]] * CIN + i];
    }
    for (int idx = tid; idx < cc * 33; idx += 256) {
      int slot = idx / 33, k = idx - slot * 33;
      float v;
      if (k == 32) v = 1.f;
      else {
        int e = es[slot];
        v = fmaxf(ea[e*3+0] * W1[k] + ea[e*3+1] * W1[32 + k] + ea[e*3+2] * W1[64 + k] + b1[k], 0.f);
      }
      zs[slot][k] = v;
    }
    __syncthreads();
    if (tid < K1) {
      int k = tid / CIN, i = tid - (tid / CIN) * CIN;
      float a = acc;
      for (int c = 0; c < cc; c++) a += zs[c][k] * hs[c][i];
      acc = a;
    }
    __syncthreads();
  }
  const size_t rowb = (size_t)n * Kpad;
  if (tid < K1) {
    uint16_t hi, lo;
    split_bf(acc * scale, hi, lo);
    Shi[rowb + tid] = hi;
    Slo[rowb + tid] = lo;
  }
  if (tid < CIN) {
    uint16_t hi, lo;
    split_bf(h[(size_t)n * CIN + tid], hi, lo);
    Shi[rowb + K1 + tid] = hi;
    Slo[rowb + K1 + tid] = lo;
  }
  for (int ki = KT + tid; ki < Kpad; ki += 256) {
    Shi[rowb + ki] = 0;
    Slo[rowb + ki] = 0;
  }
}

// ---------------- 128xBN MFMA bf16x3 GEMM, global_load_lds + XOR-swizzle + LDS dbuf ----------------
// LDS layout per buffer: [AH | AL | BH | BL], each region row-major [rows][64] u16 (128B rows, linear).
// Swizzle (bijective involution): logical elem block b of row r stored at slot b ^ (r&7). Staging keeps
// LDS dest linear (global_load_lds requirement) and applies the inverse swizzle to the per-lane GLOBAL
// source; ds_read applies the same XOR. Fragment reads land 2-way bank aliased (free, m136).
template<int BN>
__global__ __launch_bounds__(256) void mfma_gemm2_k(const uint16_t* __restrict__ Ahi,
                                                    const uint16_t* __restrict__ Alo,
                                                    const uint16_t* __restrict__ Bhi,
                                                    const uint16_t* __restrict__ Blo,
                                                    float* __restrict__ Cpart,
                                                    int Kpad, int Ncol, int M,
                                                    int totalIters) {
  constexpr int BM = 128;
  constexpr int FN = BN / 32;           // N-frags per wave (wave tile = 64 x BN/2)
  constexpr int NCA = BM / 32;          // 4KB staging chunks per A array
  constexpr int NCB = BN / 32;
  constexpr int OAH = 0;
  constexpr int OAL = BM * 64;
  constexpr int OBH = 2 * BM * 64;
  constexpr int OBL = 2 * BM * 64 + BN * 64;
  constexpr int BUFSZ = (2 * BM + 2 * BN) * 64;   // u16 per buffer
  __shared__ uint16_t smem[2 * BUFSZ] __attribute__((aligned(16)));

  const int m0 = blockIdx.x * BM;
  const int n0 = blockIdx.y * BN;
  const int SK = gridDim.z;
  const int z  = blockIdx.z;
  const int itBeg = (int)((long long)totalIters * z / SK);        // balanced split-K
  const int itEnd = (int)((long long)totalIters * (z + 1) / SK);
  const int nsteps = itEnd - itBeg;

  const int tid  = threadIdx.x;
  const int lane = tid & 63;
  const int wave = tid >> 6;
  const int wm = wave & 1, wn = wave >> 1;
  const int q  = lane >> 4;
  const int mr = lane & 15;

  // staging geometry: thread covers row (chunk*32 + tid/8), 16B slot (tid&7), inverse-swizzled source
  const int srow = tid >> 3;                               // 0..31
  const int swz  = ((tid & 7) ^ (srow & 7)) << 3;          // element offset within 64-elem row
  size_t aoff[NCA], boff[NCB];
#pragma unroll
  for (int c = 0; c < NCA; c++)
    aoff[c] = (size_t)(m0 + c * 32 + srow) * Kpad + swz + (size_t)itBeg * 64;
#pragma unroll
  for (int c = 0; c < NCB; c++)
    boff[c] = (size_t)(n0 + c * 32 + srow) * Kpad + swz + (size_t)itBeg * 64;
  const int wlds = wave << 9;   // u16: this wave's 1KB slice within each 4KB chunk

  f32x4 acc[4][FN];
#pragma unroll
  for (int a = 0; a < 4; a++)
#pragma unroll
    for (int b = 0; b < FN; b++) acc[a][b] = (f32x4)0.f;

  auto stage = [&](int buf, int t) {
    uint16_t* base = smem + buf * BUFSZ;
    const size_t ka = (size_t)t * 64;
#pragma unroll
    for (int c = 0; c < NCA; c++) {
      glds16(Ahi + aoff[c] + ka, base + OAH + c * 2048 + wlds);
      glds16(Alo + aoff[c] + ka, base + OAL + c * 2048 + wlds);
    }
#pragma unroll
    for (int c = 0; c < NCB; c++) {
      glds16(Bhi + boff[c] + ka, base + OBH + c * 2048 + wlds);
      glds16(Blo + boff[c] + ka, base + OBL + c * 2048 + wlds);
    }
  };

  if (nsteps > 0) stage(0, 0);
  for (int t = 0; t < nsteps; t++) {
    __syncthreads();                       // drains vmcnt(0): buf[t&1] staged & prev reads done
    if (t + 1 < nsteps) stage((t & 1) ^ 1, t + 1);   // prefetch hides under this step's compute
    const uint16_t* B_ = smem + (t & 1) * BUFSZ;
#pragma unroll
    for (int ks = 0; ks < 2; ks++) {
      const int e0 = (ks * 32 + q * 8) ^ ((mr & 7) << 3);
      bf16x8 ah[4], al[4], bh[FN], bl[FN];
#pragma unroll
      for (int f = 0; f < 4; f++) {
        const int row = wm * 64 + f * 16 + mr;
        ah[f] = *(const bf16x8*)&B_[OAH + row * 64 + e0];
        al[f] = *(const bf16x8*)&B_[OAL + row * 64 + e0];
      }
#pragma unroll
      for (int f = 0; f < FN; f++) {
        const int row = wn * (BN / 2) + f * 16 + mr;
        bh[f] = *(const bf16x8*)&B_[OBH + row * 64 + e0];
        bl[f] = *(const bf16x8*)&B_[OBL + row * 64 + e0];
      }
#pragma unroll
      for (int fm = 0; fm < 4; fm++)
#pragma unroll
        for (int fn = 0; fn < FN; fn++) {
          acc[fm][fn] = __builtin_amdgcn_mfma_f32_16x16x32_bf16(ah[fm], bh[fn], acc[fm][fn], 0, 0, 0);
          acc[fm][fn] = __builtin_amdgcn_mfma_f32_16x16x32_bf16(ah[fm], bl[fn], acc[fm][fn], 0, 0, 0);
          acc[fm][fn] = __builtin_amdgcn_mfma_f32_16x16x32_bf16(al[fm], bh[fn], acc[fm][fn], 0, 0, 0);
        }
    }
  }

  // D row = quad*4 + reg, col = lane&15 (verified layout)
  float* Cz = Cpart + (size_t)z * M * Ncol;
#pragma unroll
  for (int fm = 0; fm < 4; fm++)
#pragma unroll
    for (int reg = 0; reg < 4; reg++) {
      const int row = m0 + wm * 64 + fm * 16 + q * 4 + reg;
#pragma unroll
      for (int fn = 0; fn < FN; fn++) {
        const int col = n0 + wn * (BN / 2) + fn * 16 + mr;
        Cz[(size_t)row * Ncol + col] = acc[fm][fn][reg];
      }
    }
}

// ---------------- split-K reduce + bias + BN + ReLU epilogue ----------------
__global__ void epilogue_k(const float* __restrict__ Cpart, int SK, size_t plane4,
                           int Ncol,
                           const float* __restrict__ bias, const float* __restrict__ bg,
                           const float* __restrict__ bb, const float* __restrict__ bnm,
                           const float* __restrict__ bnv,
                           float* __restrict__ C, int total4) {
  int i = blockIdx.x * blockDim.x + threadIdx.x;
  if (i >= total4) return;
  float4 v = {0.f, 0.f, 0.f, 0.f};
  for (int z = 0; z < SK; z++) {
    float4 p = *((const float4*)Cpart + (size_t)z * plane4 + i);
    v.x += p.x; v.y += p.y; v.z += p.z; v.w += p.w;
  }
  int col0 = (i * 4) % Ncol;
  float o[4] = {v.x, v.y, v.z, v.w};
#pragma unroll
  for (int j = 0; j < 4; j++) {
    int c = col0 + j;
    float s = bg[c] * rsqrtf(bnv[c] + BN_EPS);
    float val = (o[j] + bias[c] - bnm[c]) * s + bb[c];
    o[j] = fmaxf(val, 0.f);
  }
  float4 r = {o[0], o[1], o[2], o[3]};
  *((float4*)C + i) = r;
}

// ---------------- fused pool (mean over sorted batch_seg) + final MLP + LeakyReLU ----------------
__global__ __launch_bounds__(256) void pool_final_k(const float* __restrict__ h,
                                                    const int* __restrict__ seg,
                                                    const float* __restrict__ W,
                                                    const float* __restrict__ b,
                                                    float* __restrict__ out,
                                                    int N, int T) {
  __shared__ float pooled[256];
  const int g = blockIdx.x, tid = threadIdx.x;
  int lo = 0, hi = N;
  while (lo < hi) { int mid = (lo + hi) >> 1; if (seg[mid] < g) lo = mid + 1; else hi = mid; }
  int lo2 = lo, hi2 = N;
  while (lo2 < hi2) { int mid = (lo2 + hi2) >> 1; if (seg[mid] < g + 1) lo2 = mid + 1; else hi2 = mid; }
  const int cnt = lo2 - lo;
  const float inv = 1.f / fmaxf((float)cnt, 1.f);
  float s = 0.f;
  for (int n = lo; n < lo2; n++) s += h[(size_t)n * 256 + tid];
  pooled[tid] = s * inv;
  __syncthreads();
  if (tid < T) {
    float acc = b[tid];
    for (int o = 0; o < 256; o++) acc += pooled[o] * W[(size_t)o * T + tid];
    out[(size_t)g * T + tid] = (acc > 0.f) ? acc : 0.1f * acc;
  }
}

// ---------------- host orchestration ----------------
extern "C" void kernel_launch(void* const* d_in, const int* in_sizes, int n_in,
                              void* d_out, int out_size, void* d_ws, size_t ws_size,
                              hipStream_t stream) {
  const float* x   = (const float*)d_in[0];
  const int*   ei  = (const int*)d_in[1];
  const float* ea  = (const float*)d_in[2];
  const int*   seg = (const int*)d_in[3];

  const int N = in_sizes[0] / 5;       // 4096
  const int E = in_sizes[2] / 3;       // 16384
  const int T = in_sizes[35];          // 100
  const int G = out_size / T;          // 128
  const int* src = ei;
  const int* dst = ei + E;

  const float *W1[3], *b1[3], *W2[3], *b2[3], *root[3], *bias[3];
  const float *bng[3], *bnb[3], *bnm[3], *bnv[3];
  for (int l = 0; l < 3; l++) {
    int base = 4 + l * 10;
    W1[l]   = (const float*)d_in[base + 0];
    b1[l]   = (const float*)d_in[base + 1];
    W2[l]   = (const float*)d_in[base + 2];
    b2[l]   = (const float*)d_in[base + 3];
    root[l] = (const float*)d_in[base + 4];
    bias[l] = (const float*)d_in[base + 5];
    bng[l]  = (const float*)d_in[base + 6];
    bnb[l]  = (const float*)d_in[base + 7];
    bnm[l]  = (const float*)d_in[base + 8];
    bnv[l]  = (const float*)d_in[base + 9];
  }
  const float* mlpW = (const float*)d_in[34];
  const float* mlpb = (const float*)d_in[35];

  char* p = (char*)d_ws;
  auto carve = [&](size_t bytes) -> char* {
    char* r = p;
    p += (bytes + 255) & ~(size_t)255;
    return r;
  };
  const int KPADMAX = 4352;
  const int SKMAX = 8;
  int*      cnt     = (int*)carve((size_t)N * 4);
  int*      offsets = (int*)carve((size_t)(N + 1) * 4);
  int*      cursor  = (int*)carve((size_t)N * 4);
  int*      csr     = (int*)carve((size_t)E * 4);
  uint16_t* Whi     = (uint16_t*)carve((size_t)256 * KPADMAX * 2);
  uint16_t* Wlo     = (uint16_t*)carve((size_t)256 * KPADMAX * 2);
  uint16_t* Shi     = (uint16_t*)carve((size_t)N * KPADMAX * 2);
  uint16_t* Slo     = (uint16_t*)carve((size_t)N * KPADMAX * 2);
  float*    Cpart   = (float*)carve((size_t)SKMAX * N * 256 * 4 / 2);  // 8*4096*128 or 4*4096*256
  float*    hA      = (float*)carve((size_t)N * 256 * 4);
  float*    hB      = (float*)carve((size_t)N * 128 * 4);

  // CSR over dst
  zero_i32_k<<<(N + 255) / 256, 256, 0, stream>>>(cnt, N);
  hist_k<<<(E + 255) / 256, 256, 0, stream>>>(dst, cnt, E);
  scan_k<<<1, 1024, 0, stream>>>(cnt, offsets, cursor, N, E);
  scatter_k<<<(E + 255) / 256, 256, 0, stream>>>(dst, cursor, csr, E);

  const int cins[3]  = {5, 64, 128};
  const int couts[3] = {64, 128, 256};
  const int kpads[3] = {192, 2176, 4352};
  const int sks[3]   = {3, 8, 4};

  const float* hin = x;
  float* houts[3] = {hA, hB, hA};

  for (int l = 0; l < 3; l++) {
    int cin = cins[l], cout = couts[l], Kpad = kpads[l], SK = sks[l];
    int iters = Kpad / 64;
    build_W2pT_k<<<(cout * Kpad + 255) / 256, 256, 0, stream>>>(W2[l], b2[l], root[l],
                                                                Whi, Wlo, cin, cout, Kpad);
    if (cin == 5)
      build_S5_k<<<N, 256, 0, stream>>>(hin, ea, W1[l], b1[l], src, csr, offsets, Shi, Slo, Kpad);
    else if (cin == 64)
      build_S_vec_k<64><<<N, 256, 0, stream>>>(hin, ea, W1[l], b1[l], src, csr, offsets, Shi, Slo, Kpad);
    else
      build_S_vec_k<128><<<N, 256, 0, stream>>>(hin, ea, W1[l], b1[l], src, csr, offsets, Shi, Slo, Kpad);

    if (cout >= 128) {
      dim3 grid(N / 128, cout / 128, SK);
      mfma_gemm2_k<128><<<grid, 256, 0, stream>>>(Shi, Slo, Whi, Wlo, Cpart,
                                                  Kpad, cout, N, iters);
    } else {
      dim3 grid(N / 128, 1, SK);
      mfma_gemm2_k<64><<<grid, 256, 0, stream>>>(Shi, Slo, Whi, Wlo, Cpart,
                                                 Kpad, cout, N, iters);
    }

    int total4 = N * cout / 4;
    epilogue_k<<<(total4 + 255) / 256, 256, 0, stream>>>(Cpart, SK, (size_t)N * cout / 4, cout,
                                                         bias[l], bng[l], bnb[l], bnm[l], bnv[l],
                                                         houts[l], total4);
    hin = houts[l];
  }

  pool_final_k<<<G, 256, 0, stream>>>(hA, seg, mlpW, mlpb, (float*)d_out, N, T);
}